// Round 6
// baseline (314.842 us; speedup 1.0000x reference)
//
#include <hip/hip_runtime.h>
#include <math.h>

#define HH 240
#define WW 320
#define HWSZ (240*320)
#define NN 2

// Workspace layout (bytes)
#define OFF_BW1   0         // conv1 fp16 frags: 36t*4m*1024B = 147456
#define OFF_BW3   147456    // conv3 fp16 frags: 18t*4m*1024B = 73728
#define OFF_W2A   221184    // bases-GEMM A frags: 8*1024 = 8192
#define OFF_COEFA 229376    // coef-GEMM A frags: 48*1024 = 49152
#define OFF_BN    278528    // [sbr(64), bbr2(64), s3(64), o3(64)] f32 = 1024
#define OFF_U     279552    // u: 2*64*76800 f32

typedef __attribute__((ext_vector_type(8))) _Float16 half8v;
typedef __attribute__((ext_vector_type(4))) _Float16 half4v;
typedef __attribute__((ext_vector_type(4))) float f32x4;

// ---------------- prep: fp16 weight frag packing + BN folds ----------------
// tasks: BW1 9216, BW3 4608, W2A 512, COEFA 3072, bn 128 => 17536 -> 69 blocks
__global__ void prep_k(const float* __restrict__ w1, const float* __restrict__ w3,
                       const float* __restrict__ w2, const float* __restrict__ coef,
                       const float* __restrict__ coef_bias,
                       const float* __restrict__ brg, const float* __restrict__ brb,
                       const float* __restrict__ brm, const float* __restrict__ brv,
                       const float* __restrict__ g3, const float* __restrict__ b3,
                       const float* __restrict__ m3, const float* __restrict__ v3,
                       float* __restrict__ ws) {
    int id = blockIdx.x * 256 + threadIdx.x;
    _Float16* hw = (_Float16*)ws;

    if (id < 9216) {    // conv1 frags: frag = g*4 + m, g = cc*9 + t
        int l = id & 63; int f = id >> 6;   // 0..143
        int m = f & 3;   int g = f >> 2;    // 0..35
        int t = g % 9, cc = g / 9;
        _Float16* dst = hw + OFF_BW1/2 + (size_t)(g*4 + m)*512 + l*8;
        #pragma unroll
        for (int j = 0; j < 8; ++j) {
            int ci = cc*32 + (l>>4)*8 + j;
            int co = m*16 + (l&15);
            dst[j] = (_Float16)w1[(co*128 + ci)*9 + t];
        }
        return;
    }
    id -= 9216;
    if (id < 4608) {    // conv3 frags
        int l = id & 63; int f = id >> 6;   // 0..71
        int m = f & 3;   int g = f >> 2;    // 0..17
        int t = g % 9, cc = g / 9;
        _Float16* dst = hw + OFF_BW3/2 + (size_t)(g*4 + m)*512 + l*8;
        #pragma unroll
        for (int j = 0; j < 8; ++j) {
            int ci = cc*32 + (l>>4)*8 + j;
            int co = m*16 + (l&15);
            dst[j] = (_Float16)w3[(co*64 + ci)*9 + t];
        }
        return;
    }
    id -= 4608;
    if (id < 512) {     // W2A: A[row=j 54pad64][k=c 64]
        int l = id & 63; int f = id >> 6;   // 0..7
        int mf = f & 3, kc = f >> 2;
        int row = mf*16 + (l & 15);
        _Float16* dst = hw + OFF_W2A/2 + (size_t)((kc*4 + mf)*64 + l)*8;
        #pragma unroll
        for (int j = 0; j < 8; ++j) {
            int k = kc*32 + (l>>4)*8 + j;
            dst[j] = (row < 54) ? (_Float16)w2[row*64 + k] : (_Float16)0.f;
        }
        return;
    }
    id -= 512;
    if (id < 3072) {    // COEFA: k-order cg*96 + m_local*16 + c_local
        int l = id & 63; int f = id >> 6;   // 0..47
        int ocf = f & 3; int g2 = f >> 2;   // g2 = cg*3 + ch
        int ch = g2 % 3, cg = g2 / 3;
        int oc = ocf*16 + (l & 15);
        _Float16* dst = hw + OFF_COEFA/2 + (size_t)((g2*4 + ocf)*64 + l)*8;
        #pragma unroll
        for (int j = 0; j < 8; ++j) {
            int k32 = (l>>4)*8 + j;
            int m = ch*2 + (k32 >> 4);
            int c = cg*16 + (k32 & 15);
            dst[j] = (_Float16)coef[oc*384 + c*6 + m];
        }
        return;
    }
    id -= 3072;
    if (id < 64) {
        float s = brg[id] * rsqrtf(brv[id] + 1e-5f);
        ws[OFF_BN/4 + id]      = s;
        ws[OFF_BN/4 + 64 + id] = coef_bias[id]*s + brb[id] - brm[id]*s;
        return;
    }
    id -= 64;
    if (id < 64) {
        float s = g3[id] * rsqrtf(v3[id] + 1e-5f);
        ws[OFF_BN/4 + 128 + id] = s;
        ws[OFF_BN/4 + 192 + id] = b3[id] - m3[id]*s;
    }
}

// ---------------- MFMA conv 3x3, v3: fp16 1-pass, 27.2KB LDS, 4 blocks/CU ----------------
// block: 256 thr = 4 waves; pixel tile 8x32; wave owns 4 px-frags x 4 co-frags.
// LDS tile [pos 340][32ch pad40] fp16, 80B rows (2-way conflict = free).
// Weights: register double-buffer from global (L2-resident), 4 frags/tap.
template<int CHUNKS, bool HAS_SCALE>
__launch_bounds__(256, 4)
__global__ void convmfma_k(const float* __restrict__ in0, const float* __restrict__ in1,
                           const _Float16* __restrict__ wfr,
                           const float* __restrict__ epiA, const float* __restrict__ epiB,
                           float* __restrict__ outp) {
    __shared__ _Float16 TILE[340*40];    // 27200 B
    const int tid = threadIdx.x;
    const int lane = tid & 63, wv = tid >> 6;
    const int l15 = lane & 15, l4 = lane >> 4;
    const int x0 = blockIdx.x * 32, y0 = blockIdx.y * 8;
    const int nb = blockIdx.z;
    const int NT = CHUNKS * 9;

    f32x4 acc[4][4];
    #pragma unroll
    for (int m = 0; m < 4; ++m)
        #pragma unroll
        for (int nf = 0; nf < 4; ++nf)
            acc[m][nf] = (f32x4){0.f, 0.f, 0.f, 0.f};

    half8v Wf[2][4];
    auto loadW = [&](int g, int b) {
        #pragma unroll
        for (int m = 0; m < 4; ++m)
            Wf[b][m] = *(const half8v*)(wfr + (size_t)(g*4 + m)*512 + lane*8);
    };
    loadW(0, 0);

    #pragma unroll
    for (int cc = 0; cc < CHUNKS; ++cc) {
        __syncthreads();               // previous tile's readers done
        const float* plane = (cc < 2) ? in0 + (size_t)(nb*64 + cc*32) * HWSZ
                                      : in1 + (size_t)(nb*64 + (cc-2)*32) * HWSZ;
        #pragma unroll
        for (int it = 0; it < 11; ++it) {
            int i = tid + it * 256;
            if (it < 10 || i < 2720) {
                int q = i / 340, p = i - q*340;
                int py = p / 34, px = p - py*34;
                int gy = y0 - 1 + py, gx = x0 - 1 + px;
                bool ok = (gy >= 0) & (gy < HH) & (gx >= 0) & (gx < WW);
                const float* sp = plane + (size_t)(q*4) * HWSZ + gy*WW + gx;
                half4v hv;
                #pragma unroll
                for (int d = 0; d < 4; ++d)
                    hv[d] = ok ? (_Float16)sp[(size_t)d * HWSZ] : (_Float16)0.f;
                *(half4v*)&TILE[p*40 + q*4] = hv;
            }
        }
        __syncthreads();               // tile visible

        #pragma unroll
        for (int t = 0; t < 9; ++t) {
            const int g = cc*9 + t;
            const int b = g & 1;
            if (g + 1 < NT) loadW(g + 1, b ^ 1);
            const int ky = t / 3, kx = t - ky*3;
            #pragma unroll
            for (int nf = 0; nf < 4; ++nf) {
                int gnf = wv*4 + nf;
                int r = gnf >> 1, h = gnf & 1;
                int pos = (r + ky)*34 + 16*h + l15 + kx;
                half8v Ph = *(const half8v*)&TILE[pos*40 + l4*8];
                #pragma unroll
                for (int m = 0; m < 4; ++m)
                    acc[m][nf] = __builtin_amdgcn_mfma_f32_16x16x32_f16(Wf[b][m], Ph, acc[m][nf], 0, 0, 0);
            }
        }
    }

    // epilogue: D row = co (16m + 4*l4 + i), col = px (l15)
    #pragma unroll
    for (int m = 0; m < 4; ++m) {
        #pragma unroll
        for (int i = 0; i < 4; ++i) {
            int co = m*16 + l4*4 + i;
            float sc  = HAS_SCALE ? epiA[co] : 1.0f;
            float ofs = HAS_SCALE ? epiB[co] : epiA[co];
            float* op = outp + (size_t)(nb*64 + co) * HWSZ;
            #pragma unroll
            for (int nf = 0; nf < 4; ++nf) {
                int gnf = wv*4 + nf;
                int r = gnf >> 1, h = gnf & 1;
                int y = y0 + r, x = x0 + 16*h + l15;
                op[y*WW + x] = fmaxf(acc[m][nf][i]*sc + ofs, 0.f);
            }
        }
    }
}

// ---------------- kernel 2 (MFMA fp16): bases + einsum + coef + BN + ReLU -> u ----------------
__launch_bounds__(256, 2)
__global__ void fuse2_k(const float* __restrict__ feat, const float* __restrict__ tin,
                        const _Float16* __restrict__ w2a,
                        const float* __restrict__ b2,
                        const _Float16* __restrict__ coefa,
                        const float* __restrict__ bn,
                        float* __restrict__ uout) {
    __shared__ _Float16 BSH[256*56];     // bases fp16 [px][54 pad 56] = 28672 B
    __shared__ float PT[340*20];         // patches f32 [pos][16 ch pad 20] = 27200 B
    const int tid = threadIdx.x;
    const int lane = tid & 63, wv = tid >> 6;
    const int l15 = lane & 15, l4 = lane >> 4;
    const int x0 = blockIdx.x*32, y0 = blockIdx.y*8;
    const int nb = blockIdx.z;

    // ---- Phase A: bases = w2 @ t (fp16 MFMA) ----
    half8v w2f[2][4];
    #pragma unroll
    for (int kc = 0; kc < 2; ++kc)
        #pragma unroll
        for (int mf = 0; mf < 4; ++mf)
            w2f[kc][mf] = *(const half8v*)(w2a + (size_t)((kc*4 + mf)*64 + lane)*8);

    f32x4 b2v[4];
    #pragma unroll
    for (int mf = 0; mf < 4; ++mf)
        #pragma unroll
        for (int i = 0; i < 4; ++i) {
            int row = mf*16 + l4*4 + i;
            b2v[mf][i] = (row < 54) ? b2[row] : 0.f;
        }

    #pragma unroll
    for (int nf = 0; nf < 4; ++nf) {
        int gnf = wv*4 + nf, r = gnf >> 1, h = gnf & 1;
        int y = y0 + r, x = x0 + 16*h + l15;
        const float* tp = tin + (size_t)nb*64*HWSZ + y*WW + x;
        half8v tf0, tf1;
        #pragma unroll
        for (int j = 0; j < 8; ++j) {
            tf0[j] = (_Float16)tp[(size_t)(l4*8 + j) * HWSZ];
            tf1[j] = (_Float16)tp[(size_t)(32 + l4*8 + j) * HWSZ];
        }
        int px = r*32 + 16*h + l15;
        #pragma unroll
        for (int mf = 0; mf < 4; ++mf) {
            f32x4 ab = (f32x4){0.f, 0.f, 0.f, 0.f};
            ab = __builtin_amdgcn_mfma_f32_16x16x32_f16(w2f[0][mf], tf0, ab, 0, 0, 0);
            ab = __builtin_amdgcn_mfma_f32_16x16x32_f16(w2f[1][mf], tf1, ab, 0, 0, 0);
            if (mf < 3 || l4 < 2) {
                half4v hv;
                #pragma unroll
                for (int i = 0; i < 4; ++i)
                    hv[i] = (_Float16)(ab[i] + b2v[mf][i]);
                *(half4v*)&BSH[px*56 + mf*16 + l4*4] = hv;   // wave-private px
            }
        }
    }

    // ---- Phase B ----
    f32x4 acc[4][4];
    #pragma unroll
    for (int m = 0; m < 4; ++m)
        #pragma unroll
        for (int nf = 0; nf < 4; ++nf)
            acc[m][nf] = (f32x4){0.f, 0.f, 0.f, 0.f};

    const int c0 = (l4 & 1) * 8;
    const int m0 = l4 >> 1;

    #pragma unroll 1
    for (int cg = 0; cg < 4; ++cg) {
        __syncthreads();
        #pragma unroll
        for (int it = 0; it < 6; ++it) {
            int task = tid + it*256;
            if (task < 1360) {
                int pos = task >> 2, cq = task & 3;
                int py = pos / 34, pxx = pos - py*34;
                int gy = y0 - 1 + py, gx = x0 - 1 + pxx;
                bool ok = (gy >= 0) & (gy < HH) & (gx >= 0) & (gx < WW);
                const float* fp = feat + (size_t)(nb*64 + cg*16 + cq*4)*HWSZ + gy*WW + gx;
                f32x4 v;
                #pragma unroll
                for (int d = 0; d < 4; ++d) v[d] = ok ? fp[(size_t)d*HWSZ] : 0.f;
                *(f32x4*)&PT[pos*20 + cq*4] = v;
            }
        }
        __syncthreads();

        half8v CA[3][4];
        #pragma unroll
        for (int ch = 0; ch < 3; ++ch)
            #pragma unroll
            for (int oc = 0; oc < 4; ++oc)
                CA[ch][oc] = *(const half8v*)(coefa + (size_t)(((cg*3 + ch)*4 + oc)*64 + lane)*8);

        #pragma unroll
        for (int nf = 0; nf < 4; ++nf) {
            int gnf = wv*4 + nf, r = gnf >> 1, h = gnf & 1;
            int px = r*32 + 16*h + l15;
            float s[3][8];
            #pragma unroll
            for (int ch = 0; ch < 3; ++ch)
                #pragma unroll
                for (int j = 0; j < 8; ++j) s[ch][j] = 0.f;

            #pragma unroll
            for (int tap = 0; tap < 9; ++tap) {
                int ky = tap / 3, kx = tap - ky*3;
                int pos = (r + ky)*34 + 16*h + l15 + kx;
                const float* pp = &PT[pos*20 + c0];
                f32x4 pa = *(const f32x4*)pp;
                f32x4 pb = *(const f32x4*)(pp + 4);
                float ba0 = (float)BSH[px*56 + (m0*9 + tap)];
                float ba1 = (float)BSH[px*56 + ((m0 + 2)*9 + tap)];
                float ba2 = (float)BSH[px*56 + ((m0 + 4)*9 + tap)];
                #pragma unroll
                for (int j = 0; j < 4; ++j) {
                    s[0][j]   = fmaf(ba0, pa[j], s[0][j]);
                    s[0][j+4] = fmaf(ba0, pb[j], s[0][j+4]);
                    s[1][j]   = fmaf(ba1, pa[j], s[1][j]);
                    s[1][j+4] = fmaf(ba1, pb[j], s[1][j+4]);
                    s[2][j]   = fmaf(ba2, pa[j], s[2][j]);
                    s[2][j+4] = fmaf(ba2, pb[j], s[2][j+4]);
                }
            }
            half8v B0, B1, B2;
            #pragma unroll
            for (int j = 0; j < 8; ++j) {
                B0[j] = (_Float16)s[0][j];
                B1[j] = (_Float16)s[1][j];
                B2[j] = (_Float16)s[2][j];
            }
            #pragma unroll
            for (int oc = 0; oc < 4; ++oc) {
                acc[oc][nf] = __builtin_amdgcn_mfma_f32_16x16x32_f16(CA[0][oc], B0, acc[oc][nf], 0, 0, 0);
                acc[oc][nf] = __builtin_amdgcn_mfma_f32_16x16x32_f16(CA[1][oc], B1, acc[oc][nf], 0, 0, 0);
                acc[oc][nf] = __builtin_amdgcn_mfma_f32_16x16x32_f16(CA[2][oc], B2, acc[oc][nf], 0, 0, 0);
            }
        }
    }

    #pragma unroll
    for (int ocf = 0; ocf < 4; ++ocf)
        #pragma unroll
        for (int i = 0; i < 4; ++i) {
            int co = ocf*16 + l4*4 + i;
            float sc = bn[co], ofs = bn[64 + co];
            float* up = uout + (size_t)(nb*64 + co)*HWSZ;
            #pragma unroll
            for (int nf = 0; nf < 4; ++nf) {
                int gnf = wv*4 + nf, r = gnf >> 1, h = gnf & 1;
                int y = y0 + r, x = x0 + 16*h + l15;
                up[y*WW + x] = fmaxf(acc[ocf][nf][i]*sc + ofs, 0.f);
            }
        }
}

extern "C" void kernel_launch(void* const* d_in, const int* in_sizes, int n_in,
                              void* d_out, int out_size, void* d_ws, size_t ws_size,
                              hipStream_t stream) {
    const float* feat      = (const float*)d_in[0];
    const float* wgt       = (const float*)d_in[1];
    const float* w1        = (const float*)d_in[2];
    const float* b1        = (const float*)d_in[3];
    const float* w2        = (const float*)d_in[4];
    const float* b2        = (const float*)d_in[5];
    const float* coef      = (const float*)d_in[6];
    const float* coef_bias = (const float*)d_in[7];
    const float* brg       = (const float*)d_in[8];
    const float* brb       = (const float*)d_in[9];
    const float* brm       = (const float*)d_in[10];
    const float* brv       = (const float*)d_in[11];
    const float* w3        = (const float*)d_in[12];
    const float* g3        = (const float*)d_in[13];
    const float* b3        = (const float*)d_in[14];
    const float* m3        = (const float*)d_in[15];
    const float* v3        = (const float*)d_in[16];

    float* out = (float*)d_out;
    float* ws  = (float*)d_ws;
    _Float16* hw = (_Float16*)ws;

    prep_k<<<69, 256, 0, stream>>>(w1, w3, w2, coef, coef_bias,
                                   brg, brb, brm, brv, g3, b3, m3, v3, ws);

    dim3 grid(WW/32, HH/8, NN);   // (10, 30, 2)

    // conv1: t -> d_out
    convmfma_k<4, false><<<grid, 256, 0, stream>>>(
        feat, wgt, hw + OFF_BW1/2, b1, b1, out);

    // fuse2: u -> ws
    fuse2_k<<<grid, 256, 0, stream>>>(feat, out,
        hw + OFF_W2A/2, b2, hw + OFF_COEFA/2, ws + OFF_BN/4, ws + OFF_U/4);

    // conv3: d_out
    convmfma_k<2, true><<<grid, 256, 0, stream>>>(
        ws + OFF_U/4, ws + OFF_U/4, hw + OFF_BW3/2,
        ws + OFF_BN/4 + 128, ws + OFF_BN/4 + 192, out);
}

// Round 7
// 220.495 us; speedup vs baseline: 1.4279x; 1.4279x over previous
//
#include <hip/hip_runtime.h>
#include <math.h>

#define HH 240
#define WW 320
#define HWSZ (240*320)
#define NN 2

// Workspace layout (bytes)
#define OFF_BW1   0         // conv1 fp16 frags: 36t*4m*1024B = 147456
#define OFF_BW3   147456    // conv3 fp16 frags: 18t*4m*1024B = 73728
#define OFF_W2A   221184    // bases-GEMM A frags: 8*1024 = 8192
#define OFF_COEFA 229376    // coef-GEMM A frags: 48*1024 = 49152
#define OFF_BN    278528    // [sbr(64), bbr2(64), s3(64), o3(64)] f32 = 1024
#define OFF_U     279552    // u: 2*64*76800 f32

typedef __attribute__((ext_vector_type(8))) _Float16 half8v;
typedef __attribute__((ext_vector_type(4))) _Float16 half4v;
typedef __attribute__((ext_vector_type(4))) float f32x4;

// ---------------- prep: fp16 weight frag packing + BN folds (unchanged) ----------------
__global__ void prep_k(const float* __restrict__ w1, const float* __restrict__ w3,
                       const float* __restrict__ w2, const float* __restrict__ coef,
                       const float* __restrict__ coef_bias,
                       const float* __restrict__ brg, const float* __restrict__ brb,
                       const float* __restrict__ brm, const float* __restrict__ brv,
                       const float* __restrict__ g3, const float* __restrict__ b3,
                       const float* __restrict__ m3, const float* __restrict__ v3,
                       float* __restrict__ ws) {
    int id = blockIdx.x * 256 + threadIdx.x;
    _Float16* hw = (_Float16*)ws;

    if (id < 9216) {    // conv1 frags: frag = g*4 + m, g = cc*9 + t
        int l = id & 63; int f = id >> 6;
        int m = f & 3;   int g = f >> 2;
        int t = g % 9, cc = g / 9;
        _Float16* dst = hw + OFF_BW1/2 + (size_t)(g*4 + m)*512 + l*8;
        #pragma unroll
        for (int j = 0; j < 8; ++j) {
            int ci = cc*32 + (l>>4)*8 + j;
            int co = m*16 + (l&15);
            dst[j] = (_Float16)w1[(co*128 + ci)*9 + t];
        }
        return;
    }
    id -= 9216;
    if (id < 4608) {    // conv3 frags
        int l = id & 63; int f = id >> 6;
        int m = f & 3;   int g = f >> 2;
        int t = g % 9, cc = g / 9;
        _Float16* dst = hw + OFF_BW3/2 + (size_t)(g*4 + m)*512 + l*8;
        #pragma unroll
        for (int j = 0; j < 8; ++j) {
            int ci = cc*32 + (l>>4)*8 + j;
            int co = m*16 + (l&15);
            dst[j] = (_Float16)w3[(co*64 + ci)*9 + t];
        }
        return;
    }
    id -= 4608;
    if (id < 512) {     // W2A: A[row=j 54pad64][k=c 64]
        int l = id & 63; int f = id >> 6;
        int mf = f & 3, kc = f >> 2;
        int row = mf*16 + (l & 15);
        _Float16* dst = hw + OFF_W2A/2 + (size_t)((kc*4 + mf)*64 + l)*8;
        #pragma unroll
        for (int j = 0; j < 8; ++j) {
            int k = kc*32 + (l>>4)*8 + j;
            dst[j] = (row < 54) ? (_Float16)w2[row*64 + k] : (_Float16)0.f;
        }
        return;
    }
    id -= 512;
    if (id < 3072) {    // COEFA: k-order cg*96 + m_local*16 + c_local
        int l = id & 63; int f = id >> 6;
        int ocf = f & 3; int g2 = f >> 2;
        int ch = g2 % 3, cg = g2 / 3;
        int oc = ocf*16 + (l & 15);
        _Float16* dst = hw + OFF_COEFA/2 + (size_t)((g2*4 + ocf)*64 + l)*8;
        #pragma unroll
        for (int j = 0; j < 8; ++j) {
            int k32 = (l>>4)*8 + j;
            int m = ch*2 + (k32 >> 4);
            int c = cg*16 + (k32 & 15);
            dst[j] = (_Float16)coef[oc*384 + c*6 + m];
        }
        return;
    }
    id -= 3072;
    if (id < 64) {
        float s = brg[id] * rsqrtf(brv[id] + 1e-5f);
        ws[OFF_BN/4 + id]      = s;
        ws[OFF_BN/4 + 64 + id] = coef_bias[id]*s + brb[id] - brm[id]*s;
        return;
    }
    id -= 64;
    if (id < 64) {
        float s = g3[id] * rsqrtf(v3[id] + 1e-5f);
        ws[OFF_BN/4 + 128 + id] = s;
        ws[OFF_BN/4 + 192 + id] = b3[id] - m3[id]*s;
    }
}

// ---------------- MFMA conv 3x3, v4: fp16 1-pass, 16x8 tile, 1200 blocks ----------------
// block: 256 thr = 4 waves; pixel tile 8 rows x 16 cols; wave wv owns rows 2wv,2wv+1
// (nf 0..1) x all 4 co-frags. LDS tile [180 pos][32ch pad40] fp16 = 14.4 KB.
// Weights: register double-buffer from L2 (4 frags/tap).
template<int CHUNKS, bool HAS_SCALE>
__launch_bounds__(256, 2)
__global__ void convmfma_k(const float* __restrict__ in0, const float* __restrict__ in1,
                           const _Float16* __restrict__ wfr,
                           const float* __restrict__ epiA, const float* __restrict__ epiB,
                           float* __restrict__ outp) {
    __shared__ _Float16 TILE[180*40];    // 14400 B
    const int tid = threadIdx.x;
    const int lane = tid & 63, wv = tid >> 6;
    const int l15 = lane & 15, l4 = lane >> 4;
    const int x0 = blockIdx.x * 16, y0 = blockIdx.y * 8;
    const int nb = blockIdx.z;
    const int NT = CHUNKS * 9;

    f32x4 acc[4][2];
    #pragma unroll
    for (int m = 0; m < 4; ++m)
        #pragma unroll
        for (int nf = 0; nf < 2; ++nf)
            acc[m][nf] = (f32x4){0.f, 0.f, 0.f, 0.f};

    half8v Wf[2][4];
    auto loadW = [&](int g, int b) {
        #pragma unroll
        for (int m = 0; m < 4; ++m)
            Wf[b][m] = *(const half8v*)(wfr + (size_t)(g*4 + m)*512 + lane*8);
    };
    loadW(0, 0);

    #pragma unroll
    for (int cc = 0; cc < CHUNKS; ++cc) {
        __syncthreads();               // previous tile's readers done
        const float* plane = (cc < 2) ? in0 + (size_t)(nb*64 + cc*32) * HWSZ
                                      : in1 + (size_t)(nb*64 + (cc-2)*32) * HWSZ;
        #pragma unroll
        for (int it = 0; it < 6; ++it) {
            int i = tid + it * 256;
            if (i < 1440) {
                int q = i / 180, p = i - q*180;
                int py = p / 18, px = p - py*18;
                int gy = y0 - 1 + py, gx = x0 - 1 + px;
                bool ok = (gy >= 0) & (gy < HH) & (gx >= 0) & (gx < WW);
                const float* sp = plane + (size_t)(q*4) * HWSZ + gy*WW + gx;
                half4v hv;
                #pragma unroll
                for (int d = 0; d < 4; ++d)
                    hv[d] = ok ? (_Float16)sp[(size_t)d * HWSZ] : (_Float16)0.f;
                *(half4v*)&TILE[p*40 + q*4] = hv;
            }
        }
        __syncthreads();               // tile visible

        #pragma unroll
        for (int t = 0; t < 9; ++t) {
            const int g = cc*9 + t;
            const int b = g & 1;
            if (g + 1 < NT) loadW(g + 1, b ^ 1);
            const int ky = t / 3, kx = t - ky*3;
            #pragma unroll
            for (int nf = 0; nf < 2; ++nf) {
                int r = wv*2 + nf;
                int pos = (r + ky)*18 + l15 + kx;
                half8v Ph = *(const half8v*)&TILE[pos*40 + l4*8];
                #pragma unroll
                for (int m = 0; m < 4; ++m)
                    acc[m][nf] = __builtin_amdgcn_mfma_f32_16x16x32_f16(Wf[b][m], Ph, acc[m][nf], 0, 0, 0);
            }
        }
    }

    // epilogue: D row = co (16m + 4*l4 + i), col = px (l15)
    #pragma unroll
    for (int m = 0; m < 4; ++m) {
        #pragma unroll
        for (int i = 0; i < 4; ++i) {
            int co = m*16 + l4*4 + i;
            float sc  = HAS_SCALE ? epiA[co] : 1.0f;
            float ofs = HAS_SCALE ? epiB[co] : epiA[co];
            float* op = outp + (size_t)(nb*64 + co) * HWSZ;
            #pragma unroll
            for (int nf = 0; nf < 2; ++nf) {
                int y = y0 + wv*2 + nf, x = x0 + l15;
                op[y*WW + x] = fmaxf(acc[m][nf][i]*sc + ofs, 0.f);
            }
        }
    }
}

// ---------------- kernel 2 (MFMA fp16), 16x8 tile ----------------
__launch_bounds__(256, 2)
__global__ void fuse2_k(const float* __restrict__ feat, const float* __restrict__ tin,
                        const _Float16* __restrict__ w2a,
                        const float* __restrict__ b2,
                        const _Float16* __restrict__ coefa,
                        const float* __restrict__ bn,
                        float* __restrict__ uout) {
    __shared__ _Float16 BSH[128*56];     // bases fp16 [px][54 pad 56] = 14336 B
    __shared__ float PT[180*20];         // patches f32 [pos][16 ch pad 20] = 14400 B
    const int tid = threadIdx.x;
    const int lane = tid & 63, wv = tid >> 6;
    const int l15 = lane & 15, l4 = lane >> 4;
    const int x0 = blockIdx.x*16, y0 = blockIdx.y*8;
    const int nb = blockIdx.z;

    // ---- Phase A: bases = w2 @ t (fp16 MFMA) ----
    half8v w2f[2][4];
    #pragma unroll
    for (int kc = 0; kc < 2; ++kc)
        #pragma unroll
        for (int mf = 0; mf < 4; ++mf)
            w2f[kc][mf] = *(const half8v*)(w2a + (size_t)((kc*4 + mf)*64 + lane)*8);

    f32x4 b2v[4];
    #pragma unroll
    for (int mf = 0; mf < 4; ++mf)
        #pragma unroll
        for (int i = 0; i < 4; ++i) {
            int row = mf*16 + l4*4 + i;
            b2v[mf][i] = (row < 54) ? b2[row] : 0.f;
        }

    #pragma unroll
    for (int nf = 0; nf < 2; ++nf) {
        int r = wv*2 + nf;
        int y = y0 + r, x = x0 + l15;
        const float* tp = tin + (size_t)nb*64*HWSZ + y*WW + x;
        half8v tf0, tf1;
        #pragma unroll
        for (int j = 0; j < 8; ++j) {
            tf0[j] = (_Float16)tp[(size_t)(l4*8 + j) * HWSZ];
            tf1[j] = (_Float16)tp[(size_t)(32 + l4*8 + j) * HWSZ];
        }
        int px = r*16 + l15;
        #pragma unroll
        for (int mf = 0; mf < 4; ++mf) {
            f32x4 ab = (f32x4){0.f, 0.f, 0.f, 0.f};
            ab = __builtin_amdgcn_mfma_f32_16x16x32_f16(w2f[0][mf], tf0, ab, 0, 0, 0);
            ab = __builtin_amdgcn_mfma_f32_16x16x32_f16(w2f[1][mf], tf1, ab, 0, 0, 0);
            if (mf < 3 || l4 < 2) {
                half4v hv;
                #pragma unroll
                for (int i = 0; i < 4; ++i)
                    hv[i] = (_Float16)(ab[i] + b2v[mf][i]);
                *(half4v*)&BSH[px*56 + mf*16 + l4*4] = hv;   // wave-private px
            }
        }
    }

    // ---- Phase B ----
    f32x4 acc[4][2];
    #pragma unroll
    for (int m = 0; m < 4; ++m)
        #pragma unroll
        for (int nf = 0; nf < 2; ++nf)
            acc[m][nf] = (f32x4){0.f, 0.f, 0.f, 0.f};

    const int c0 = (l4 & 1) * 8;
    const int m0 = l4 >> 1;

    #pragma unroll 1
    for (int cg = 0; cg < 4; ++cg) {
        __syncthreads();
        #pragma unroll
        for (int it = 0; it < 3; ++it) {
            int task = tid + it*256;
            if (task < 720) {
                int pos = task >> 2, cq = task & 3;
                int py = pos / 18, pxx = pos - py*18;
                int gy = y0 - 1 + py, gx = x0 - 1 + pxx;
                bool ok = (gy >= 0) & (gy < HH) & (gx >= 0) & (gx < WW);
                const float* fp = feat + (size_t)(nb*64 + cg*16 + cq*4)*HWSZ + gy*WW + gx;
                f32x4 v;
                #pragma unroll
                for (int d = 0; d < 4; ++d) v[d] = ok ? fp[(size_t)d*HWSZ] : 0.f;
                *(f32x4*)&PT[pos*20 + cq*4] = v;
            }
        }
        __syncthreads();

        half8v CA[3][4];
        #pragma unroll
        for (int ch = 0; ch < 3; ++ch)
            #pragma unroll
            for (int oc = 0; oc < 4; ++oc)
                CA[ch][oc] = *(const half8v*)(coefa + (size_t)(((cg*3 + ch)*4 + oc)*64 + lane)*8);

        #pragma unroll
        for (int nf = 0; nf < 2; ++nf) {
            int r = wv*2 + nf;
            int px = r*16 + l15;
            float s[3][8];
            #pragma unroll
            for (int ch = 0; ch < 3; ++ch)
                #pragma unroll
                for (int j = 0; j < 8; ++j) s[ch][j] = 0.f;

            #pragma unroll
            for (int tap = 0; tap < 9; ++tap) {
                int ky = tap / 3, kx = tap - ky*3;
                int pos = (r + ky)*18 + l15 + kx;
                const float* pp = &PT[pos*20 + c0];
                f32x4 pa = *(const f32x4*)pp;
                f32x4 pb = *(const f32x4*)(pp + 4);
                float ba0 = (float)BSH[px*56 + (m0*9 + tap)];
                float ba1 = (float)BSH[px*56 + ((m0 + 2)*9 + tap)];
                float ba2 = (float)BSH[px*56 + ((m0 + 4)*9 + tap)];
                #pragma unroll
                for (int j = 0; j < 4; ++j) {
                    s[0][j]   = fmaf(ba0, pa[j], s[0][j]);
                    s[0][j+4] = fmaf(ba0, pb[j], s[0][j+4]);
                    s[1][j]   = fmaf(ba1, pa[j], s[1][j]);
                    s[1][j+4] = fmaf(ba1, pb[j], s[1][j+4]);
                    s[2][j]   = fmaf(ba2, pa[j], s[2][j]);
                    s[2][j+4] = fmaf(ba2, pb[j], s[2][j+4]);
                }
            }
            half8v B0, B1, B2;
            #pragma unroll
            for (int j = 0; j < 8; ++j) {
                B0[j] = (_Float16)s[0][j];
                B1[j] = (_Float16)s[1][j];
                B2[j] = (_Float16)s[2][j];
            }
            #pragma unroll
            for (int oc = 0; oc < 4; ++oc) {
                acc[oc][nf] = __builtin_amdgcn_mfma_f32_16x16x32_f16(CA[0][oc], B0, acc[oc][nf], 0, 0, 0);
                acc[oc][nf] = __builtin_amdgcn_mfma_f32_16x16x32_f16(CA[1][oc], B1, acc[oc][nf], 0, 0, 0);
                acc[oc][nf] = __builtin_amdgcn_mfma_f32_16x16x32_f16(CA[2][oc], B2, acc[oc][nf], 0, 0, 0);
            }
        }
    }

    #pragma unroll
    for (int ocf = 0; ocf < 4; ++ocf)
        #pragma unroll
        for (int i = 0; i < 4; ++i) {
            int co = ocf*16 + l4*4 + i;
            float sc = bn[co], ofs = bn[64 + co];
            float* up = uout + (size_t)(nb*64 + co)*HWSZ;
            #pragma unroll
            for (int nf = 0; nf < 2; ++nf) {
                int y = y0 + wv*2 + nf, x = x0 + l15;
                up[y*WW + x] = fmaxf(acc[ocf][nf][i]*sc + ofs, 0.f);
            }
        }
}

extern "C" void kernel_launch(void* const* d_in, const int* in_sizes, int n_in,
                              void* d_out, int out_size, void* d_ws, size_t ws_size,
                              hipStream_t stream) {
    const float* feat      = (const float*)d_in[0];
    const float* wgt       = (const float*)d_in[1];
    const float* w1        = (const float*)d_in[2];
    const float* b1        = (const float*)d_in[3];
    const float* w2        = (const float*)d_in[4];
    const float* b2        = (const float*)d_in[5];
    const float* coef      = (const float*)d_in[6];
    const float* coef_bias = (const float*)d_in[7];
    const float* brg       = (const float*)d_in[8];
    const float* brb       = (const float*)d_in[9];
    const float* brm       = (const float*)d_in[10];
    const float* brv       = (const float*)d_in[11];
    const float* w3        = (const float*)d_in[12];
    const float* g3        = (const float*)d_in[13];
    const float* b3        = (const float*)d_in[14];
    const float* m3        = (const float*)d_in[15];
    const float* v3        = (const float*)d_in[16];

    float* out = (float*)d_out;
    float* ws  = (float*)d_ws;
    _Float16* hw = (_Float16*)ws;

    prep_k<<<69, 256, 0, stream>>>(w1, w3, w2, coef, coef_bias,
                                   brg, brb, brm, brv, g3, b3, m3, v3, ws);

    dim3 grid(WW/16, HH/8, NN);   // (20, 30, 2) = 1200 blocks

    // conv1: t -> d_out
    convmfma_k<4, false><<<grid, 256, 0, stream>>>(
        feat, wgt, hw + OFF_BW1/2, b1, b1, out);

    // fuse2: u -> ws
    fuse2_k<<<grid, 256, 0, stream>>>(feat, out,
        hw + OFF_W2A/2, b2, hw + OFF_COEFA/2, ws + OFF_BN/4, ws + OFF_U/4);

    // conv3: d_out
    convmfma_k<2, true><<<grid, 256, 0, stream>>>(
        ws + OFF_U/4, ws + OFF_U/4, hw + OFF_BW3/2,
        ws + OFF_BN/4 + 128, ws + OFF_BN/4 + 192, out);
}

// Round 8
// 124.067 us; speedup vs baseline: 2.5377x; 1.7772x over previous
//
#include <hip/hip_runtime.h>
#include <math.h>

#define HH 240
#define WW 320
#define HWSZ (240*320)
#define NN 2

// Workspace layout (bytes)
#define OFF_BW1   0          // conv1 fp16 frags: 4cc*9t*4m*1024 = 147456
#define OFF_BW3   147456     // conv3 fp16 frags: 73728
#define OFF_W2A   221184     // bases-GEMM A frags: 8192
#define OFF_COEFA 229376     // coef-GEMM A frags: 49152
#define OFF_BN    278528     // [sbr(64), bbr2(64), s3(64), o3(64)] f32 = 1024
#define OFF_FHF   279552     // feat NHWC fp16: 2*76800*64*2 = 19660800
#define OFF_FHW   19940352   // wgt NHWC fp16 (u overlays it after conv1): 19660800
// total: 39,601,152 B (< 39.88 MB proven in R1)

typedef __attribute__((ext_vector_type(8))) _Float16 half8v;
typedef __attribute__((ext_vector_type(4))) _Float16 half4v;
typedef __attribute__((ext_vector_type(4))) float f32x4;

// ---------------- prep: fp16 weight frag packing + BN folds (unchanged) ----------------
__global__ void prep_k(const float* __restrict__ w1, const float* __restrict__ w3,
                       const float* __restrict__ w2, const float* __restrict__ coef,
                       const float* __restrict__ coef_bias,
                       const float* __restrict__ brg, const float* __restrict__ brb,
                       const float* __restrict__ brm, const float* __restrict__ brv,
                       const float* __restrict__ g3, const float* __restrict__ b3,
                       const float* __restrict__ m3, const float* __restrict__ v3,
                       float* __restrict__ ws) {
    int id = blockIdx.x * 256 + threadIdx.x;
    _Float16* hw = (_Float16*)ws;

    if (id < 9216) {    // conv1 frags: frag = g*4 + m, g = cc*9 + t
        int l = id & 63; int f = id >> 6;
        int m = f & 3;   int g = f >> 2;
        int t = g % 9, cc = g / 9;
        _Float16* dst = hw + OFF_BW1/2 + (size_t)(g*4 + m)*512 + l*8;
        #pragma unroll
        for (int j = 0; j < 8; ++j) {
            int ci = cc*32 + (l>>4)*8 + j;
            int co = m*16 + (l&15);
            dst[j] = (_Float16)w1[(co*128 + ci)*9 + t];
        }
        return;
    }
    id -= 9216;
    if (id < 4608) {    // conv3 frags
        int l = id & 63; int f = id >> 6;
        int m = f & 3;   int g = f >> 2;
        int t = g % 9, cc = g / 9;
        _Float16* dst = hw + OFF_BW3/2 + (size_t)(g*4 + m)*512 + l*8;
        #pragma unroll
        for (int j = 0; j < 8; ++j) {
            int ci = cc*32 + (l>>4)*8 + j;
            int co = m*16 + (l&15);
            dst[j] = (_Float16)w3[(co*64 + ci)*9 + t];
        }
        return;
    }
    id -= 4608;
    if (id < 512) {     // W2A: A[row=j 54pad64][k=c 64]
        int l = id & 63; int f = id >> 6;
        int mf = f & 3, kc = f >> 2;
        int row = mf*16 + (l & 15);
        _Float16* dst = hw + OFF_W2A/2 + (size_t)((kc*4 + mf)*64 + l)*8;
        #pragma unroll
        for (int j = 0; j < 8; ++j) {
            int k = kc*32 + (l>>4)*8 + j;
            dst[j] = (row < 54) ? (_Float16)w2[row*64 + k] : (_Float16)0.f;
        }
        return;
    }
    id -= 512;
    if (id < 3072) {    // COEFA: k-order cg*96 + m_local*16 + c_local
        int l = id & 63; int f = id >> 6;
        int ocf = f & 3; int g2 = f >> 2;
        int ch = g2 % 3, cg = g2 / 3;
        int oc = ocf*16 + (l & 15);
        _Float16* dst = hw + OFF_COEFA/2 + (size_t)((g2*4 + ocf)*64 + l)*8;
        #pragma unroll
        for (int j = 0; j < 8; ++j) {
            int k32 = (l>>4)*8 + j;
            int m = ch*2 + (k32 >> 4);
            int c = cg*16 + (k32 & 15);
            dst[j] = (_Float16)coef[oc*384 + c*6 + m];
        }
        return;
    }
    id -= 3072;
    if (id < 64) {
        float s = brg[id] * rsqrtf(brv[id] + 1e-5f);
        ws[OFF_BN/4 + id]      = s;
        ws[OFF_BN/4 + 64 + id] = coef_bias[id]*s + brb[id] - brm[id]*s;
        return;
    }
    id -= 64;
    if (id < 64) {
        float s = g3[id] * rsqrtf(v3[id] + 1e-5f);
        ws[OFF_BN/4 + 128 + id] = s;
        ws[OFF_BN/4 + 192 + id] = b3[id] - m3[id]*s;
    }
}

// ---------------- NCHW f32 -> NHWC fp16 transpose (feat & wgt) ----------------
// block: one (n, tensor, y, 64-px xblock): LDS transpose, coalesced both sides.
__global__ void nhwc_k(const float* __restrict__ feat, const float* __restrict__ wgt,
                       _Float16* __restrict__ fhf, _Float16* __restrict__ fhw) {
    __shared__ float L[64][65];
    const int tid = threadIdx.x;
    const int xb = blockIdx.x * 64, y = blockIdx.y;
    const int n = blockIdx.z >> 1, w = blockIdx.z & 1;
    const float* src = (w ? wgt : feat) + (size_t)n*64*HWSZ + y*WW + xb;
    _Float16* dst = (w ? fhw : fhf) + ((size_t)n*HWSZ + y*WW + xb) * 64;
    const int lx = tid & 63, c4 = tid >> 6;
    #pragma unroll
    for (int k = 0; k < 16; ++k) {
        int c = c4*16 + k;
        L[c][lx] = src[(size_t)c*HWSZ + lx];
    }
    __syncthreads();
    const int x = tid >> 3, c0 = (tid & 7) * 8;
    #pragma unroll
    for (int h = 0; h < 2; ++h) {
        int xx = x + h*32;
        half8v v;
        #pragma unroll
        for (int j = 0; j < 8; ++j) v[j] = (_Float16)L[c0 + j][xx];
        *(half8v*)&dst[xx*64 + c0] = v;
    }
}

// ---------------- MFMA conv 3x3, v5: NHWC fp16 in, LDS weight staging ----------------
// block: 256 thr = 4 waves; pixel tile 8x16; wave wv owns rows 2wv,2wv+1 x 4 co-frags.
// inputs: one half8v (16B, 8 contiguous channels) per task -> TILE[180 pos][32ch pad40].
// weights: 36KB/chunk global_load_lds once per chunk, ds_read_b128 per tap (no extra barriers).
template<int CHUNKS, bool HAS_SCALE>
__launch_bounds__(256, 2)
__global__ void convmfma_k(const _Float16* __restrict__ in0, const _Float16* __restrict__ in1,
                           const _Float16* __restrict__ wfr,
                           const float* __restrict__ epiA, const float* __restrict__ epiB,
                           float* __restrict__ outF, _Float16* __restrict__ outH) {
    __shared__ alignas(16) _Float16 TILE[180*40];     // 14400 B
    __shared__ alignas(16) _Float16 WLDS[36*512];     // 36864 B
    const int tid = threadIdx.x;
    const int lane = tid & 63, wv = tid >> 6;
    const int l15 = lane & 15, l4 = lane >> 4;
    const int x0 = blockIdx.x * 16, y0 = blockIdx.y * 8;
    const int nb = blockIdx.z;

    f32x4 acc[4][2];
    #pragma unroll
    for (int m = 0; m < 4; ++m)
        #pragma unroll
        for (int nf = 0; nf < 2; ++nf)
            acc[m][nf] = (f32x4){0.f, 0.f, 0.f, 0.f};

    #pragma unroll 1
    for (int cc = 0; cc < CHUNKS; ++cc) {
        __syncthreads();     // previous chunk's TILE/WLDS readers done
        // weights: wave wv DMAs segments wv*9 .. wv*9+8 (1KB each, linear dest)
        const _Float16* wsrc = wfr + (size_t)cc * 18432;
        #pragma unroll
        for (int j = 0; j < 9; ++j) {
            int seg = wv*9 + j;
            __builtin_amdgcn_global_load_lds(
                (const __attribute__((address_space(1))) unsigned int*)(wsrc + seg*512 + lane*8),
                (__attribute__((address_space(3))) unsigned int*)&WLDS[seg*512],
                16, 0, 0);
        }
        // inputs: 720 tasks x 16B (8 contiguous channels of one pixel)
        const _Float16* tens = (cc < 2) ? in0 : in1;
        const int choff = (cc & 1) * 32;
        const _Float16* base = tens + (size_t)nb * HWSZ * 64;
        #pragma unroll
        for (int it = 0; it < 3; ++it) {
            int task = tid + it*256;
            if (it < 2 || task < 720) {
                int pos = task >> 2, hh = task & 3;
                int py = pos / 18, px = pos - py*18;
                int gy = y0 - 1 + py, gx = x0 - 1 + px;
                bool ok = (gy >= 0) & (gy < HH) & (gx >= 0) & (gx < WW);
                half8v v;
                #pragma unroll
                for (int j = 0; j < 8; ++j) v[j] = (_Float16)0.f;
                if (ok) v = *(const half8v*)&base[((size_t)(gy*WW + gx))*64 + choff + hh*8];
                *(half8v*)&TILE[pos*40 + hh*8] = v;
            }
        }
        __syncthreads();     // TILE + weight DMA visible

        #pragma unroll
        for (int t = 0; t < 9; ++t) {
            half8v Wm[4];
            #pragma unroll
            for (int m = 0; m < 4; ++m)
                Wm[m] = *(const half8v*)&WLDS[(t*4 + m)*512 + lane*8];
            const int ky = t / 3, kx = t - ky*3;
            #pragma unroll
            for (int nf = 0; nf < 2; ++nf) {
                int pos = (wv*2 + nf + ky)*18 + l15 + kx;
                half8v Ph = *(const half8v*)&TILE[pos*40 + l4*8];
                #pragma unroll
                for (int m = 0; m < 4; ++m)
                    acc[m][nf] = __builtin_amdgcn_mfma_f32_16x16x32_f16(Wm[m], Ph, acc[m][nf], 0, 0, 0);
            }
        }
    }

    if (HAS_SCALE) {
        // conv3: BN + ReLU -> f32 NCHW (final output)
        #pragma unroll
        for (int m = 0; m < 4; ++m)
            #pragma unroll
            for (int i = 0; i < 4; ++i) {
                int co = m*16 + l4*4 + i;
                float sc = epiA[co], ofs = epiB[co];
                float* op = outF + (size_t)(nb*64 + co) * HWSZ;
                #pragma unroll
                for (int nf = 0; nf < 2; ++nf) {
                    int y = y0 + wv*2 + nf, x = x0 + l15;
                    op[y*WW + x] = fmaxf(acc[m][nf][i]*sc + ofs, 0.f);
                }
            }
    } else {
        // conv1: bias + ReLU -> fp16 NHWC (t)
        #pragma unroll
        for (int nf = 0; nf < 2; ++nf) {
            int y = y0 + wv*2 + nf, x = x0 + l15;
            _Float16* op = outH + ((size_t)nb*HWSZ + y*WW + x) * 64;
            #pragma unroll
            for (int m = 0; m < 4; ++m) {
                half4v hv;
                #pragma unroll
                for (int i = 0; i < 4; ++i) {
                    float v = acc[m][nf][i] + epiA[m*16 + l4*4 + i];
                    hv[i] = (_Float16)fmaxf(v, 0.f);
                }
                *(half4v*)&op[m*16 + l4*4] = hv;
            }
        }
    }
}

// ---------------- kernel 2 (MFMA fp16), NHWC in/out ----------------
__launch_bounds__(256, 2)
__global__ void fuse2_k(const _Float16* __restrict__ fhf, const _Float16* __restrict__ tH,
                        const _Float16* __restrict__ w2a,
                        const float* __restrict__ b2,
                        const _Float16* __restrict__ coefa,
                        const float* __restrict__ bn,
                        _Float16* __restrict__ uH) {
    __shared__ _Float16 BSH[128*56];     // bases fp16 [px][54 pad 56] = 14336 B
    __shared__ float PT[180*20];         // patches f32 [pos][16 ch pad 20] = 14400 B
    const int tid = threadIdx.x;
    const int lane = tid & 63, wv = tid >> 6;
    const int l15 = lane & 15, l4 = lane >> 4;
    const int x0 = blockIdx.x*16, y0 = blockIdx.y*8;
    const int nb = blockIdx.z;

    // ---- Phase A: bases = w2 @ t (fp16 MFMA); t is NHWC: 2 contiguous 16B loads ----
    half8v w2f[2][4];
    #pragma unroll
    for (int kc = 0; kc < 2; ++kc)
        #pragma unroll
        for (int mf = 0; mf < 4; ++mf)
            w2f[kc][mf] = *(const half8v*)(w2a + (size_t)((kc*4 + mf)*64 + lane)*8);

    f32x4 b2v[4];
    #pragma unroll
    for (int mf = 0; mf < 4; ++mf)
        #pragma unroll
        for (int i = 0; i < 4; ++i) {
            int row = mf*16 + l4*4 + i;
            b2v[mf][i] = (row < 54) ? b2[row] : 0.f;
        }

    #pragma unroll
    for (int nf = 0; nf < 2; ++nf) {
        int r = wv*2 + nf;
        int y = y0 + r, x = x0 + l15;
        const _Float16* tp = tH + ((size_t)nb*HWSZ + y*WW + x) * 64;
        half8v tf0 = *(const half8v*)&tp[l4*8];
        half8v tf1 = *(const half8v*)&tp[32 + l4*8];
        int px = r*16 + l15;
        #pragma unroll
        for (int mf = 0; mf < 4; ++mf) {
            f32x4 ab = (f32x4){0.f, 0.f, 0.f, 0.f};
            ab = __builtin_amdgcn_mfma_f32_16x16x32_f16(w2f[0][mf], tf0, ab, 0, 0, 0);
            ab = __builtin_amdgcn_mfma_f32_16x16x32_f16(w2f[1][mf], tf1, ab, 0, 0, 0);
            if (mf < 3 || l4 < 2) {
                half4v hv;
                #pragma unroll
                for (int i = 0; i < 4; ++i)
                    hv[i] = (_Float16)(ab[i] + b2v[mf][i]);
                *(half4v*)&BSH[px*56 + mf*16 + l4*4] = hv;   // wave-private px
            }
        }
    }

    // ---- Phase B ----
    f32x4 acc[4][2];
    #pragma unroll
    for (int m = 0; m < 4; ++m)
        #pragma unroll
        for (int nf = 0; nf < 2; ++nf)
            acc[m][nf] = (f32x4){0.f, 0.f, 0.f, 0.f};

    const int c0 = (l4 & 1) * 8;
    const int m0 = l4 >> 1;

    #pragma unroll 1
    for (int cg = 0; cg < 4; ++cg) {
        __syncthreads();
        #pragma unroll
        for (int it = 0; it < 2; ++it) {
            int task = tid + it*256;
            if (task < 360) {
                int pos = task >> 1, hh = task & 1;
                int py = pos / 18, pxx = pos - py*18;
                int gy = y0 - 1 + py, gx = x0 - 1 + pxx;
                bool ok = (gy >= 0) & (gy < HH) & (gx >= 0) & (gx < WW);
                half8v hv;
                #pragma unroll
                for (int j = 0; j < 8; ++j) hv[j] = (_Float16)0.f;
                if (ok) hv = *(const half8v*)&fhf[((size_t)nb*HWSZ + gy*WW + gx)*64 + cg*16 + hh*8];
                f32x4 a, b;
                #pragma unroll
                for (int j = 0; j < 4; ++j) { a[j] = (float)hv[j]; b[j] = (float)hv[4+j]; }
                *(f32x4*)&PT[pos*20 + hh*8]     = a;
                *(f32x4*)&PT[pos*20 + hh*8 + 4] = b;
            }
        }
        __syncthreads();

        half8v CA[3][4];
        #pragma unroll
        for (int ch = 0; ch < 3; ++ch)
            #pragma unroll
            for (int oc = 0; oc < 4; ++oc)
                CA[ch][oc] = *(const half8v*)(coefa + (size_t)(((cg*3 + ch)*4 + oc)*64 + lane)*8);

        #pragma unroll
        for (int nf = 0; nf < 2; ++nf) {
            int r = wv*2 + nf;
            int px = r*16 + l15;
            float s[3][8];
            #pragma unroll
            for (int ch = 0; ch < 3; ++ch)
                #pragma unroll
                for (int j = 0; j < 8; ++j) s[ch][j] = 0.f;

            #pragma unroll
            for (int tap = 0; tap < 9; ++tap) {
                int ky = tap / 3, kx = tap - ky*3;
                int pos = (r + ky)*18 + l15 + kx;
                const float* pp = &PT[pos*20 + c0];
                f32x4 pa = *(const f32x4*)pp;
                f32x4 pb = *(const f32x4*)(pp + 4);
                float ba0 = (float)BSH[px*56 + (m0*9 + tap)];
                float ba1 = (float)BSH[px*56 + ((m0 + 2)*9 + tap)];
                float ba2 = (float)BSH[px*56 + ((m0 + 4)*9 + tap)];
                #pragma unroll
                for (int j = 0; j < 4; ++j) {
                    s[0][j]   = fmaf(ba0, pa[j], s[0][j]);
                    s[0][j+4] = fmaf(ba0, pb[j], s[0][j+4]);
                    s[1][j]   = fmaf(ba1, pa[j], s[1][j]);
                    s[1][j+4] = fmaf(ba1, pb[j], s[1][j+4]);
                    s[2][j]   = fmaf(ba2, pa[j], s[2][j]);
                    s[2][j+4] = fmaf(ba2, pb[j], s[2][j+4]);
                }
            }
            half8v B0, B1, B2;
            #pragma unroll
            for (int j = 0; j < 8; ++j) {
                B0[j] = (_Float16)s[0][j];
                B1[j] = (_Float16)s[1][j];
                B2[j] = (_Float16)s[2][j];
            }
            #pragma unroll
            for (int oc = 0; oc < 4; ++oc) {
                acc[oc][nf] = __builtin_amdgcn_mfma_f32_16x16x32_f16(CA[0][oc], B0, acc[oc][nf], 0, 0, 0);
                acc[oc][nf] = __builtin_amdgcn_mfma_f32_16x16x32_f16(CA[1][oc], B1, acc[oc][nf], 0, 0, 0);
                acc[oc][nf] = __builtin_amdgcn_mfma_f32_16x16x32_f16(CA[2][oc], B2, acc[oc][nf], 0, 0, 0);
            }
        }
    }

    // epilogue: BN(+coef_bias)+ReLU -> u (NHWC fp16)
    #pragma unroll
    for (int nf = 0; nf < 2; ++nf) {
        int y = y0 + wv*2 + nf, x = x0 + l15;
        _Float16* up = uH + ((size_t)nb*HWSZ + y*WW + x) * 64;
        #pragma unroll
        for (int ocf = 0; ocf < 4; ++ocf) {
            half4v hv;
            #pragma unroll
            for (int i = 0; i < 4; ++i) {
                int co = ocf*16 + l4*4 + i;
                hv[i] = (_Float16)fmaxf(acc[ocf][nf][i]*bn[co] + bn[64 + co], 0.f);
            }
            *(half4v*)&up[ocf*16 + l4*4] = hv;
        }
    }
}

extern "C" void kernel_launch(void* const* d_in, const int* in_sizes, int n_in,
                              void* d_out, int out_size, void* d_ws, size_t ws_size,
                              hipStream_t stream) {
    const float* feat      = (const float*)d_in[0];
    const float* wgt       = (const float*)d_in[1];
    const float* w1        = (const float*)d_in[2];
    const float* b1        = (const float*)d_in[3];
    const float* w2        = (const float*)d_in[4];
    const float* b2        = (const float*)d_in[5];
    const float* coef      = (const float*)d_in[6];
    const float* coef_bias = (const float*)d_in[7];
    const float* brg       = (const float*)d_in[8];
    const float* brb       = (const float*)d_in[9];
    const float* brm       = (const float*)d_in[10];
    const float* brv       = (const float*)d_in[11];
    const float* w3        = (const float*)d_in[12];
    const float* g3        = (const float*)d_in[13];
    const float* b3        = (const float*)d_in[14];
    const float* m3        = (const float*)d_in[15];
    const float* v3        = (const float*)d_in[16];

    float* out = (float*)d_out;
    _Float16* tH = (_Float16*)d_out;          // t lives in d_out (fp16 NHWC, 19.7MB of 39.3MB)
    float* ws  = (float*)d_ws;
    _Float16* hw = (_Float16*)ws;
    _Float16* FHf = hw + OFF_FHF/2;
    _Float16* FHw = hw + OFF_FHW/2;           // wgt NHWC; reused as u after conv1

    prep_k<<<69, 256, 0, stream>>>(w1, w3, w2, coef, coef_bias,
                                   brg, brb, brm, brv, g3, b3, m3, v3, ws);

    nhwc_k<<<dim3(5, 240, 4), 256, 0, stream>>>(feat, wgt, FHf, FHw);

    dim3 grid(WW/16, HH/8, NN);   // (20, 30, 2) = 1200 blocks

    // conv1: t (fp16 NHWC) -> d_out
    convmfma_k<4, false><<<grid, 256, 0, stream>>>(
        FHf, FHw, hw + OFF_BW1/2, b1, b1, nullptr, tH);

    // fuse2: u (fp16 NHWC) -> FHw region (wgt copy is dead now)
    fuse2_k<<<grid, 256, 0, stream>>>(FHf, tH,
        hw + OFF_W2A/2, b2, hw + OFF_COEFA/2, ws + OFF_BN/4, FHw);

    // conv3: final f32 NCHW -> d_out
    convmfma_k<2, true><<<grid, 256, 0, stream>>>(
        FHw, FHw, hw + OFF_BW3/2,
        ws + OFF_BN/4 + 128, ws + OFF_BN/4 + 192, out, nullptr);
}